// Round 8
// baseline (134.917 us; speedup 1.0000x reference)
//
#include <hip/hip_runtime.h>

typedef __fp16 f16;
typedef __fp16 f16x8 __attribute__((ext_vector_type(8)));
typedef __fp16 f16x4 __attribute__((ext_vector_type(4)));
typedef __fp16 f16x2 __attribute__((ext_vector_type(2)));
typedef float f32x4 __attribute__((ext_vector_type(4)));
typedef float f32x16 __attribute__((ext_vector_type(16)));

#define D_MODEL 1024
#define SEQ 2048
#define NH 16
#define MTOT 4096  // B*S

typedef const __attribute__((address_space(1))) unsigned int* gp1_t;
typedef __attribute__((address_space(3))) unsigned int* lp3_t;

__device__ __forceinline__ void gload_lds16(const void* g, void* l) {
  __builtin_amdgcn_global_load_lds((gp1_t)g, (lp3_t)l, 16, 0, 0);
}

// Z-row r' -> AO superrow j (the reference's transpose/view bug, closed form)
__device__ __forceinline__ int permrow(int r) {
  int bp = r >> 11, u = (r >> 7) & 15, t = r & 127;
  int g16 = (bp << 4) | u;
  return ((((g16 & 1) << 4) | (g16 >> 1)) << 7) + t;  // (b*16+h)*128 + t
}

__device__ __forceinline__ unsigned int pkrtz(float a, float b) {
  union { f16x2 h; unsigned int u; } z;
  z.h = __builtin_amdgcn_cvt_pkrtz(a, b);
  return z.u;
}

// ---------------- weights-only convert: wT (transposed f16) for 4 matrices ----------------
__global__ __launch_bounds__(256) void cvt_all(const float* __restrict__ wq,
                                               const float* __restrict__ wk,
                                               const float* __restrict__ wv,
                                               const float* __restrict__ wo,
                                               f16* __restrict__ wT) {
  __shared__ float tl[64][65];
  int bb = blockIdx.x, tid = threadIdx.x;
  int mat = bb >> 8, tile = bb & 255;
  int tk = (tile >> 4) << 6, tn = (tile & 15) << 6;
  const float* W = mat == 0 ? wq : mat == 1 ? wk : mat == 2 ? wv : wo;
  int rr = tid >> 4, c4 = (tid & 15) << 2;
#pragma unroll
  for (int it = 0; it < 4; ++it) {
    const float* p = W + (size_t)(tk + it * 16 + rr) * D_MODEL + tn + c4;
    float4 val = *(const float4*)p;
    tl[it * 16 + rr][c4 + 0] = val.x;
    tl[it * 16 + rr][c4 + 1] = val.y;
    tl[it * 16 + rr][c4 + 2] = val.z;
    tl[it * 16 + rr][c4 + 3] = val.w;
  }
  __syncthreads();
  int n = tid & 63, kseg = (tid >> 6) << 4;
  f16x8 lo, hi;
#pragma unroll
  for (int j = 0; j < 8; ++j) lo[j] = (f16)tl[kseg + j][n];
#pragma unroll
  for (int j = 0; j < 8; ++j) hi[j] = (f16)tl[kseg + 8 + j][n];
  f16* d = wT + (size_t)mat * (D_MODEL * D_MODEL) + (size_t)(tn + n) * D_MODEL + tk + kseg;
  *(f16x8*)d = lo;
  *(f16x8*)(d + 8) = hi;
}

// ---------------- fused QKV projection GEMM v6: 128x128 tile, BK=64, double-buffer,
// A staged DIRECTLY from fp32 (reg-stage: contiguous 128B f32 read -> pkrtz -> swizzled
// ds_write_b128), B staged f16 via global_load_lds (verified inverse-swizzle path).
// Eliminates the separate qkv fp32->f16 convert pass entirely. 4 waves of 64x64,
// LDS 64 KB static -> 2 blocks/CU; grid (32,8,3) = full coverage + backfill.
__global__ __launch_bounds__(256, 2) void gemm_qkv(const float* __restrict__ q32,
                                                   const float* __restrict__ k32,
                                                   const float* __restrict__ v32,
                                                   const f16* __restrict__ wT,
                                                   const float* __restrict__ bq,
                                                   const float* __restrict__ bk,
                                                   const float* __restrict__ bv,
                                                   f16* __restrict__ Q16,
                                                   f16* __restrict__ K16,
                                                   f16* __restrict__ VT16) {
  __shared__ __attribute__((aligned(16))) f16 As[2][128 * 64];
  __shared__ __attribute__((aligned(16))) f16 Bs[2][128 * 64];
  const int K = D_MODEL, N = D_MODEL;
  const size_t WEL = (size_t)D_MODEL * D_MODEL;
  int z = blockIdx.z;
  const float* A32 = z == 0 ? q32 : z == 1 ? k32 : v32;
  const f16* BT = wT + (size_t)z * WEL;
  const float* bias = z == 0 ? bq : z == 1 ? bk : bv;

  int tid = threadIdx.x;
  int w = tid >> 6, lane = tid & 63;
  int g = lane >> 4, c = lane & 15;
  int wr = w >> 1, wc = w & 1;
  int m0 = blockIdx.x * 128, n0 = blockIdx.y * 128;
  f32x4 acc[4][4] = {};

  // ---- A reg-stage geometry: thread -> (row, half). One contiguous 128 B fp32 read
  // per K-step; 4 swizzled ds_write_b128 (write slot (h*4+u)^(row&7); read slot
  // (kk*4+g)^(row&7) -> content kk*4+g, matching the verified fragment layout).
  int arow = tid >> 1, ah = tid & 1;
  const float* Ag = A32 + (size_t)(m0 + arow) * K + ah * 32;
  char* AwBase0 = (char*)&As[0][0];
  char* AwBase1 = (char*)&As[1][0];
  int awoff[4];
#pragma unroll
  for (int u = 0; u < 4; ++u)
    awoff[u] = (arow * 128 + ah * 64 + u * 16) ^ ((arow & 7) << 4);

  // ---- B staging geometry (verified round-2 path): pre-swizzled source, linear dest.
#define STAGE_B(kt, bi)                                                       \
  {                                                                           \
    _Pragma("unroll") for (int i = 0; i < 4; ++i) {                           \
      int seg = w * 4 + i;                                                    \
      int p = seg * 1024 + lane * 16;                                         \
      int row = p >> 7;                                                       \
      int colb = (p & 127) ^ ((row & 7) << 4);                                \
      int ae = (kt) + (colb >> 1);                                            \
      gload_lds16(BT + (size_t)(n0 + row) * K + ae, &Bs[bi][seg * 512]);      \
    }                                                                         \
  }

#define LOAD_A(kt)                                                            \
  {                                                                           \
    const float4* a4 = (const float4*)(Ag + (kt));                            \
    _Pragma("unroll") for (int j = 0; j < 8; ++j) av[j] = a4[j];              \
  }

#define WRITE_A(base)                                                         \
  {                                                                           \
    _Pragma("unroll") for (int u = 0; u < 4; ++u) {                           \
      union { unsigned int uu[4]; f16x8 v; } pw;                              \
      pw.uu[0] = pkrtz(av[2 * u].x, av[2 * u].y);                             \
      pw.uu[1] = pkrtz(av[2 * u].z, av[2 * u].w);                             \
      pw.uu[2] = pkrtz(av[2 * u + 1].x, av[2 * u + 1].y);                     \
      pw.uu[3] = pkrtz(av[2 * u + 1].z, av[2 * u + 1].w);                     \
      *(f16x8*)((base) + awoff[u]) = pw.v;                                    \
    }                                                                         \
  }

  float4 av[8];
  // prologue: stage tile 0 into buf 0
  LOAD_A(0)
  STAGE_B(0, 0)
  WRITE_A(AwBase0)
  __syncthreads();

  for (int kt = 0; kt < K; kt += 64) {
    int cur = (kt >> 6) & 1, nxt = cur ^ 1;
    bool pre = (kt + 64) < K;
    if (pre) {
      LOAD_A(kt + 64)
      STAGE_B(kt + 64, nxt)
    }
    const char* Ac = (const char*)&As[cur][0];
    const char* Bc = (const char*)&Bs[cur][0];
    f16x8 af[4][2], bf[4][2];
#pragma unroll
    for (int m = 0; m < 4; ++m)
#pragma unroll
      for (int kk = 0; kk < 2; ++kk) {
        int row = wr * 64 + m * 16 + c;
        int tb = (row * 128 + kk * 64 + g * 16) ^ ((row & 7) << 4);
        af[m][kk] = *(const f16x8*)(Ac + tb);
      }
#pragma unroll
    for (int n = 0; n < 4; ++n)
#pragma unroll
      for (int kk = 0; kk < 2; ++kk) {
        int row = wc * 64 + n * 16 + c;
        int tb = (row * 128 + kk * 64 + g * 16) ^ ((row & 7) << 4);
        bf[n][kk] = *(const f16x8*)(Bc + tb);
      }
    __builtin_amdgcn_s_setprio(1);
#pragma unroll
    for (int m = 0; m < 4; ++m)
#pragma unroll
      for (int n = 0; n < 4; ++n)
#pragma unroll
        for (int kk = 0; kk < 2; ++kk)
          acc[m][n] = __builtin_amdgcn_mfma_f32_16x16x32_f16(af[m][kk], bf[n][kk], acc[m][n], 0, 0, 0);
    __builtin_amdgcn_s_setprio(0);
    if (pre) WRITE_A(nxt ? AwBase1 : AwBase0)
    __syncthreads();
  }

  int rb = m0 + wr * 64;
  int cb = n0 + wc * 64;
  if (z < 2) {
    f16* O = z == 0 ? Q16 : K16;
#pragma unroll
    for (int m = 0; m < 4; ++m) {
      int row0 = rb + m * 16 + 4 * g;
#pragma unroll
      for (int n = 0; n < 4; ++n) {
        int col = cb + n * 16 + c;
        float bv2 = bias[col];
#pragma unroll
        for (int r = 0; r < 4; ++r) O[(size_t)(row0 + r) * N + col] = (f16)(acc[m][n][r] + bv2);
      }
    }
  } else {
    f16* O = VT16;
#pragma unroll
    for (int m = 0; m < 4; ++m) {
      int s0f = rb + m * 16 + 4 * g;
      int bb = s0f >> 11, ss = s0f & (SEQ - 1);
#pragma unroll
      for (int n = 0; n < 4; ++n) {
        int col = cb + n * 16 + c;
        float bv2 = bias[col];
        f16x4 hv;
#pragma unroll
        for (int r = 0; r < 4; ++r) hv[r] = (f16)(acc[m][n][r] + bv2);
        *(f16x4*)(O + ((size_t)(bb * NH + (col >> 6)) * 64 + (col & 63)) * SEQ + ss) = hv;
      }
    }
  }
}

// ---------------- O-projection GEMM: 64x128 tiles, permuted A rows, f32 out ----------------
__global__ __launch_bounds__(256, 2) void gemm_out(const f16* __restrict__ A,
                                                   const f16* __restrict__ BT,
                                                   const float* __restrict__ bias,
                                                   float* __restrict__ O) {
  const int K = D_MODEL, N = D_MODEL;
  __shared__ f16 As[64 * 64];
  __shared__ f16 Bs[128 * 64];
  int tid = threadIdx.x;
  int w = tid >> 6, lane = tid & 63;
  int g = lane >> 4, c = lane & 15;
  int wr = w >> 1, wc = w & 1;
  int m0 = blockIdx.x * 64, n0 = blockIdx.y * 128;
  f32x4 acc[2][4] = {};

  for (int kt = 0; kt < K; kt += 64) {
#pragma unroll
    for (int i = 0; i < 2; ++i) {
      int seg = w * 2 + i;
      int p = seg * 1024 + lane * 16;
      int row = p >> 7;
      int colb = (p & 127) ^ ((row & 7) << 4);
      int ae = kt + (colb >> 1);
      gload_lds16(A + (size_t)permrow(m0 + row) * K + ae, &As[seg * 512]);
    }
#pragma unroll
    for (int i = 0; i < 4; ++i) {
      int seg = w * 4 + i;
      int p = seg * 1024 + lane * 16;
      int row = p >> 7;
      int colb = (p & 127) ^ ((row & 7) << 4);
      int ae = kt + (colb >> 1);
      gload_lds16(BT + (size_t)(n0 + row) * K + ae, &Bs[seg * 512]);
    }
    __syncthreads();
    f16x8 af[2][2], bf[4][2];
#pragma unroll
    for (int m = 0; m < 2; ++m) {
#pragma unroll
      for (int kk = 0; kk < 2; ++kk) {
        int row = wr * 32 + m * 16 + c;
        int tb = (row * 128 + kk * 64 + g * 16) ^ ((row & 7) << 4);
        af[m][kk] = *(const f16x8*)((const char*)As + tb);
      }
    }
#pragma unroll
    for (int n = 0; n < 4; ++n) {
#pragma unroll
      for (int kk = 0; kk < 2; ++kk) {
        int row = wc * 64 + n * 16 + c;
        int tb = (row * 128 + kk * 64 + g * 16) ^ ((row & 7) << 4);
        bf[n][kk] = *(const f16x8*)((const char*)Bs + tb);
      }
    }
    __builtin_amdgcn_s_setprio(1);
#pragma unroll
    for (int m = 0; m < 2; ++m)
#pragma unroll
      for (int n = 0; n < 4; ++n)
#pragma unroll
        for (int kk = 0; kk < 2; ++kk)
          acc[m][n] = __builtin_amdgcn_mfma_f32_16x16x32_f16(af[m][kk], bf[n][kk], acc[m][n], 0, 0, 0);
    __builtin_amdgcn_s_setprio(0);
    __syncthreads();
  }

  int rb = m0 + wr * 32;
  int cb = n0 + wc * 64;
#pragma unroll
  for (int m = 0; m < 2; ++m) {
    int row0 = rb + m * 16 + 4 * g;
#pragma unroll
    for (int n = 0; n < 4; ++n) {
      int col = cb + n * 16 + c;
      float bv = bias[col];
#pragma unroll
      for (int r = 0; r < 4; ++r) O[(size_t)(row0 + r) * N + col] = acc[m][n][r] + bv;
    }
  }
}

// ---------------- causal flash attention v7 (verified ~41 us): kv-parity split + flash merge ----------------
#define THR2 11.5f  // defer-max threshold, log2 domain
__global__ __launch_bounds__(256, 2) void attn_kernel(const f16* __restrict__ Q,
                                                      const f16* __restrict__ K,
                                                      const f16* __restrict__ VT,
                                                      f16* __restrict__ AO) {
  __shared__ __attribute__((aligned(16))) f16 Ksh[2][2][64 * 64];  // [buf][par] 32 KB
  __shared__ __attribute__((aligned(16))) f16 Vsh[2][2][64 * 64];  // 32 KB
  const int BUFO = 2 * 64 * 64;  // f16 elems between buf0/buf1
  int tid = threadIdx.x;
  int w = tid >> 6, lane = tid & 63;
  int c = lane & 31, hi = lane >> 5;
  int qh = w & 1, par = w >> 1;
  int blk = blockIdx.x;
  int bh = blk & 31;        // low bits -> head pinned per XCD
  int uu = blk >> 5;
  int cb = 31 - uu;         // big chunks first -> backfill-friendly schedule
  int b = bh >> 4, h = bh & 15;
  int q0 = cb * 64 + qh * 32;
  const int NT = cb + 1;
  const size_t brow = (size_t)b * SEQ;
  const int hcol = h * 64;

  // staging geometry: wave (qh,par) stages tile (t0+par), rows qh*32 + j*8 + (lane>>3)
  int sr = lane >> 3;
  int seo = ((lane & 7) ^ sr) << 3;
  const f16* Kgb = K + (size_t)(brow + qh * 32 + sr) * D_MODEL + hcol + seo;  // + kv*D_MODEL
  const f16* Vgb = VT + ((size_t)bh * 64 + qh * 32 + sr) * SEQ + seo;         // + kv
  f16* Kshf = &Ksh[0][0][0];
  f16* Vshf = &Vsh[0][0][0];
  f16* KshW = Kshf + par * 4096 + qh * 32 * 64;
  f16* VshW = Vshf + par * 4096 + qh * 32 * 64;

  // Q B-fragments (col=q-row=c, k = 16*kk + 8*hi + j), pre-scaled by log2e
  const f16 LOG2E = (f16)1.44269504f;
  f16x8 qf[4];
  const f16* Qp = Q + (size_t)(brow + q0 + c) * D_MODEL + hcol + 8 * hi;
#pragma unroll
  for (int kk = 0; kk < 4; ++kk) {
    qf[kk] = *(const f16x8*)(Qp + 16 * kk);
#pragma unroll
    for (int j = 0; j < 8; ++j) qf[kk][j] = (f16)(qf[kk][j] * LOG2E);
  }

  float m_st = -1e30f, l_st = 0.f;
  f32x16 o0 = {}, o1 = {};  // O^T accumulators, d-tiles 0..31 / 32..63; col=q per lane

  // prologue: stage pair {0,1} into buf 0 (this wave: tile par, if it exists)
  if (par < NT) {
    int kv = par * 64;
#pragma unroll
    for (int j = 0; j < 4; ++j) {
      gload_lds16(Kgb + (size_t)(kv + j * 8) * D_MODEL, KshW + (j * 8) * 64);
      gload_lds16(Vgb + (size_t)(j * 8) * SEQ + kv, VshW + (j * 8) * 64);
    }
  }
  __syncthreads();

  int rsw = (c & 7) << 4;
  int cur = 0;
  const int U = (NT + 1) >> 1;
  for (int u = 0; u < U; ++u) {
    int tpre = 2 * u + 2 + par;
    if (tpre < NT) {
      int kv = tpre * 64;
      f16* kd = KshW + (cur ^ 1) * BUFO;
      f16* vd = VshW + (cur ^ 1) * BUFO;
#pragma unroll
      for (int j = 0; j < 4; ++j) {
        gload_lds16(Kgb + (size_t)(kv + j * 8) * D_MODEL, kd + (j * 8) * 64);
        gload_lds16(Vgb + (size_t)(j * 8) * SEQ + kv, vd + (j * 8) * 64);
      }
    }
    int t = 2 * u + par;
    if (t < NT) {
      const char* Kb = (const char*)(Kshf + cur * BUFO + par * 4096);
      const char* Vb = (const char*)(Vshf + cur * BUFO + par * 4096);
      // ---- QK^T swapped: S^T[kv][q] = K . Q^T ----
      f16x8 kf[2][4];
#pragma unroll
      for (int ks = 0; ks < 2; ++ks)
#pragma unroll
        for (int kk = 0; kk < 4; ++kk)
          kf[ks][kk] = *(const f16x8*)(Kb + (((ks * 32 + c) * 128 + 32 * kk + 16 * hi) ^ rsw));
      f32x16 s0 = {}, s1 = {};
      __builtin_amdgcn_s_setprio(1);
#pragma unroll
      for (int kk = 0; kk < 4; ++kk) {
        s0 = __builtin_amdgcn_mfma_f32_32x32x16_f16(kf[0][kk], qf[kk], s0, 0, 0, 0);
        s1 = __builtin_amdgcn_mfma_f32_32x32x16_f16(kf[1][kk], qf[kk], s1, 0, 0, 0);
      }
      __builtin_amdgcn_s_setprio(0);
      // hoist V reads: independent of softmax, covers ds latency under VALU
      f16x8 vf[2][4];
#pragma unroll
      for (int dt = 0; dt < 2; ++dt)
#pragma unroll
        for (int kk = 0; kk < 4; ++kk)
          vf[dt][kk] = *(const f16x8*)(Vb + (((dt * 32 + c) * 128 + 32 * kk + 16 * hi) ^ rsw));
      // ---- causal mask (diagonal tile only); kv = 64t + 32ks + (r&3)+8(r>>2)+4hi ----
      if (t == NT - 1) {
        int q = q0 + c;
        int kvb = t * 64 + 4 * hi;
#pragma unroll
        for (int r = 0; r < 16; ++r) {
          int kv = kvb + (r & 3) + 8 * (r >> 2);
          if (kv > q) s0[r] = -1e30f;
          if (kv + 32 > q) s1[r] = -1e30f;
        }
      }
      // ---- online softmax: each lane holds 32 scores of ONE q-row (other half at lane^32) ----
      float t8[8];
#pragma unroll
      for (int r = 0; r < 8; ++r)
        t8[r] = fmaxf(fmaxf(s0[r], s0[r + 8]), fmaxf(s1[r], s1[r + 8]));
      float pm = fmaxf(fmaxf(fmaxf(t8[0], t8[1]), fmaxf(t8[2], t8[3])),
                       fmaxf(fmaxf(t8[4], t8[5]), fmaxf(t8[6], t8[7])));
      float mx = fmaxf(pm, __shfl_xor(pm, 32));
      if (__any(mx > m_st + THR2)) {
        float mnew = fmaxf(m_st, mx);
        float corr = __builtin_amdgcn_exp2f(m_st - mnew);
        l_st *= corr;
#pragma unroll
        for (int r = 0; r < 16; ++r) { o0[r] *= corr; o1[r] *= corr; }
        m_st = mnew;
      }
      float ts[16];
#pragma unroll
      for (int r = 0; r < 16; ++r) {
        float p0 = __builtin_amdgcn_exp2f(s0[r] - m_st);  // <= 2^11.5, f16-safe
        float p1 = __builtin_amdgcn_exp2f(s1[r] - m_st);
        s0[r] = p0; s1[r] = p1;
        ts[r] = p0 + p1;
      }
#pragma unroll
      for (int st = 8; st > 0; st >>= 1)
#pragma unroll
        for (int r = 0; r < st; ++r) ts[r] += ts[r + st];
      l_st += ts[0];
      // ---- P -> PV B-fragments in-register (cvt_pkrtz pairs + permlane32 hi/lo swap) ----
      union PU { unsigned int u[4]; f16x8 v; };
      PU pu[4];
#pragma unroll
      for (int kk = 0; kk < 4; ++kk) {
        int rb = 8 * (kk & 1);
        unsigned int la0, la1, lb0, lb1;
        if (kk < 2) {
          la0 = pkrtz(s0[rb + 0], s0[rb + 1]);
          la1 = pkrtz(s0[rb + 2], s0[rb + 3]);
          lb0 = pkrtz(s0[rb + 4], s0[rb + 5]);
          lb1 = pkrtz(s0[rb + 6], s0[rb + 7]);
        } else {
          la0 = pkrtz(s1[rb + 0], s1[rb + 1]);
          la1 = pkrtz(s1[rb + 2], s1[rb + 3]);
          lb0 = pkrtz(s1[rb + 4], s1[rb + 5]);
          lb1 = pkrtz(s1[rb + 6], s1[rb + 7]);
        }
        asm("v_permlane32_swap_b32 %0, %1" : "+v"(la0), "+v"(lb0));
        asm("v_permlane32_swap_b32 %0, %1" : "+v"(la1), "+v"(lb1));
        pu[kk].u[0] = la0; pu[kk].u[1] = la1; pu[kk].u[2] = lb0; pu[kk].u[3] = lb1;
      }
      // ---- PV: O^T[d][q] += V^T[d][kv] * P^T[kv][q] ----
      __builtin_amdgcn_s_setprio(1);
#pragma unroll
      for (int kk = 0; kk < 4; ++kk) {
        o0 = __builtin_amdgcn_mfma_f32_32x32x16_f16(vf[0][kk], pu[kk].v, o0, 0, 0, 0);
        o1 = __builtin_amdgcn_mfma_f32_32x32x16_f16(vf[1][kk], pu[kk].v, o1, 0, 0, 0);
      }
      __builtin_amdgcn_s_setprio(0);
    }
    __syncthreads();
    cur ^= 1;
  }

  // ---- flash merge of parity partials (exact): par1 publishes, par0 combines ----
  float* sc = (float*)Kshf;  // K LDS dead after loop; 128 x 34 f32 = 17 KB
  int mb = (qh * 64 + lane) * 34;
  if (par == 1) {
    sc[mb] = m_st;
    sc[mb + 1] = l_st;
#pragma unroll
    for (int r = 0; r < 16; ++r) { sc[mb + 2 + r] = o0[r]; sc[mb + 18 + r] = o1[r]; }
  }
  __syncthreads();
  if (par == 0) {
    float m1 = sc[mb], l1 = sc[mb + 1];
    float mm = fmaxf(m_st, m1);
    float c0 = __builtin_amdgcn_exp2f(m_st - mm);
    float c1 = __builtin_amdgcn_exp2f(m1 - mm);
    float l = l_st * c0 + l1 * c1;
#pragma unroll
    for (int r = 0; r < 16; ++r) {
      o0[r] = o0[r] * c0 + sc[mb + 2 + r] * c1;
      o1[r] = o1[r] * c0 + sc[mb + 18 + r] * c1;
    }
    // combine hi/lo kv-half row sums, normalize, write AO[bh][s][64]
    float lt = l + __shfl_xor(l, 32);
    float linv = 1.0f / lt;
    f16* aoq = AO + ((size_t)bh * SEQ + q0 + c) * 64 + 4 * hi;
#pragma unroll
    for (int rq = 0; rq < 4; ++rq) {
      f16x4 h0, h1;
#pragma unroll
      for (int r = 0; r < 4; ++r) {
        h0[r] = (f16)(o0[4 * rq + r] * linv);
        h1[r] = (f16)(o1[4 * rq + r] * linv);
      }
      *(f16x4*)(aoq + 8 * rq) = h0;
      *(f16x4*)(aoq + 32 + 8 * rq) = h1;
    }
  }
}

extern "C" void kernel_launch(void* const* d_in, const int* in_sizes, int n_in,
                              void* d_out, int out_size, void* d_ws, size_t ws_size,
                              hipStream_t stream) {
  const float* q  = (const float*)d_in[0];
  const float* k  = (const float*)d_in[1];
  const float* v  = (const float*)d_in[2];
  const float* wq = (const float*)d_in[3];
  const float* bq = (const float*)d_in[4];
  const float* wk = (const float*)d_in[5];
  const float* bk = (const float*)d_in[6];
  const float* wv = (const float*)d_in[7];
  const float* bv = (const float*)d_in[8];
  const float* wo = (const float*)d_in[9];
  const float* bo = (const float*)d_in[10];

  const size_t TEN = (size_t)MTOT * D_MODEL;
  const size_t WEL = (size_t)D_MODEL * D_MODEL;
  f16* ws  = (f16*)d_ws;
  f16* q16 = ws;                 // region now only used as AO scratch
  f16* wT  = q16 + 3 * TEN;
  f16* Q16 = wT + 4 * WEL;
  f16* K16 = Q16 + TEN;
  f16* VT16 = K16 + TEN;
  f16* AO  = q16;

  cvt_all<<<1024, 256, 0, stream>>>(wq, wk, wv, wo, wT);
  gemm_qkv<<<dim3(32, 8, 3), 256, 0, stream>>>(q, k, v, wT, bq, bk, bv, Q16, K16, VT16);
  attn_kernel<<<1024, 256, 0, stream>>>(Q16, K16, VT16, AO);
  gemm_out<<<dim3(64, 8), 256, 0, stream>>>(AO, wT + 3 * WEL, bo, (float*)d_out);
}